// Round 5
// baseline (98.207 us; speedup 1.0000x reference)
//
#include <hip/hip_runtime.h>
#include <math.h>

#define NT_ 365
#define NS_ 1024
#define NH_ 64
#define NG_ 32
#define NW_ 514        // NH*8 + 2
#define CH_ 64         // timesteps per chunk (= wave size)
#define NCHUNK_ 6      // ceil(365/64); tail steps are harmless dummies
#define YPAD_ 65       // padded row stride: bank = (lane+j)%32, conflict-free R/W
#define WPB_ 8         // waves per block -> 2 waves/SIMD on 128 CUs (TLP!)

__device__ __forceinline__ float sigmoidf(float v) {
  return 1.0f / (1.0f + expf(-v));
}

// met = (Ps, Pl, relu(Ta), E); relu folded here since gm > 0
__device__ __forceinline__ float4 compute_met(float4 xv) {
  const float P = xv.x, E = xv.y, T1 = xv.z, T2 = xv.w;
  const float Ta = (T1 + T2) * 0.5f;
  float rP;
  if (T2 <= 0.0f) {
    rP = 0.0f;
  } else if (T1 >= 0.0f) {
    rP = 1.0f;
  } else {
    float r = (T1 + T2) / (T2 - T1);
    r = fminf(fmaxf(r, -0.999999f), 0.999999f);
    rP = 1.0f - acosf(r) * (1.0f / 3.1415f);
  }
  float4 m;
  m.x = (1.0f - rP) * P;   // Ps
  m.y = rP * P;            // Pl
  m.z = fmaxf(Ta, 0.0f);   // relu(Ta)
  m.w = E;
  return m;
}

// one wave (64 lanes) per site; lane = hidden unit; met staged lane = timestep.
// 8 waves/block on 128 blocks -> 2 waves/SIMD: HW round-robin hides the
// recurrence dependency stalls that static scheduling could not (R3/R4).
__global__ __launch_bounds__(512) void waternet_scan(
    const float* __restrict__ x,     // [NT, NS, 4]
    const float* __restrict__ xc,    // [NS, NG]
    const float* __restrict__ fc_w,  // [NW, NG]
    const float* __restrict__ fc_b,  // [NW]
    float* __restrict__ out)         // [NT, NS]
{
  __shared__ float  ytile[WPB_][CH_ * YPAD_]; // 133.1 KB, per-wave slices
  __shared__ float4 smet[WPB_][CH_];          // 8 KB, per-wave met buffers

  const int tid  = threadIdx.x;
  const int lane = tid & 63;
  const int wv   = tid >> 6;
  const int site = (blockIdx.x << 3) + wv;
  const int us   = __builtin_amdgcn_readfirstlane(site);
  const float4* xp = (const float4*)x;

  // chunk-0 prefetch first: HBM latency hides under the gate GEMM
  float4 xcur = xp[lane * NS_ + site];  // t = lane

  // ---- prologue GEMM: w[site, j] = xc[site,:] . fc_w[j,:] + fc_b[j]
  float acc[8];
#pragma unroll
  for (int k = 0; k < 8; ++k) acc[k] = fc_b[k * NH_ + lane];
  float accq = fc_b[NW_ - 1];

  const float4* xcq = (const float4*)(xc + us * NG_);
  const float4* wq4 = (const float4*)fc_w;
#pragma unroll
  for (int g4 = 0; g4 < NG_ / 4; ++g4) {
    const float4 xv = xcq[g4];
#pragma unroll
    for (int k = 0; k < 8; ++k) {
      const float4 w = wq4[(k * NH_ + lane) * (NG_ / 4) + g4];
      acc[k] = fmaf(xv.x, w.x, acc[k]);
      acc[k] = fmaf(xv.y, w.y, acc[k]);
      acc[k] = fmaf(xv.z, w.z, acc[k]);
      acc[k] = fmaf(xv.w, w.w, acc[k]);
    }
    {
      const float4 w = wq4[(NW_ - 1) * (NG_ / 4) + g4];
      accq = fmaf(xv.x, w.x, accq);
      accq = fmaf(xv.y, w.y, accq);
      accq = fmaf(xv.z, w.z, accq);
      accq = fmaf(xv.w, w.w, accq);
    }
  }

  // ---- gates (per-lane = per hidden unit)
  const float gm = expf(acc[0]) + 1.0f;
  const float ge = sigmoidf(acc[1]) * 2.0f;
  const float go = sigmoidf(acc[2]);
  const float gl = expf(acc[3] * 2.0f);
  float mx = acc[4];
#pragma unroll
  for (int mm = 32; mm >= 1; mm >>= 1) mx = fmaxf(mx, __shfl_xor(mx, mm, 64));
  const float ex = expf(acc[4] - mx);
  float sm = ex;
#pragma unroll
  for (int mm = 32; mm >= 1; mm >>= 1) sm += __shfl_xor(sm, mm, 64);
  const float ga = ex / sm;
  const float gb = sigmoidf(acc[5]);
  const float kb = sigmoidf(acc[6]) * 0.1f;
  const float gi = sigmoidf(acc[7]);
  const float qb = fmaxf(accq, 0.0f) * (1.0f / NH_);
  const float kb1m = 1.0f - kb;                 // G0n = G*(1-kb)
  const float nge  = -ge;
  const float gq1  = go * (1.0f - gb) - 1.0f;   // y = ga*(H + M*gq1 + G*kb)

  // ---- scan state
  float S0 = 0.0f, H0 = 0.0f, G0 = 0.0f;

  // stage chunk-0 met (lane = timestep); per-wave DS ops are in-order, no barrier
  smet[wv][lane] = compute_met(xcur);

  // 18-VALU step; y via folded Q1+Q2+Q3
  auto step = [&](const float4 mt, float* ywaddr) {
    const float melt = mt.z * gm;                   // relu(Ta)*gm
    const float dmx  = fmaxf(S0 - melt, 0.0f);      // = S0 - Sm
    const float hs   = H0 + S0;                     // H0 + Sm = hs - dmx
    S0 = dmx + mt.x;                                // S0' = Ps + dmx
    const float t3 = fmaf(mt.y, gi, hs - dmx);      // + Pl*gi
    const float H  = fmaxf(fmaf(mt.w, nge, t3), 0.0f);
    const float M  = fminf(H, gl);
    const float Q2a = M * go;
    H0 = fminf(H - Q2a, gl);
    const float G = fmaf(Q2a, gb, G0);
    G0 = G * kb1m;
    *ywaddr = fmaf(G, kb, fmaf(M, gq1, H)) * ga;    // ga*(Q1+Q2+Q3)
  };

  float*       yw = &ytile[wv][lane];         // step j writes yw[j*YPAD_]
  const float* yr = &ytile[wv][lane * YPAD_]; // reduce: lane sums its row

  for (int c = 0; c < NCHUNK_; ++c) {
    // prefetch chunk c+1 (clamped dummy for the tail) — in flight all chunk
    int tn = (c + 1) * CH_ + lane;
    tn = (tn < NT_) ? tn : (NT_ - 1);
    const float4 xnext = xp[tn * NS_ + site];

    const float4* mp = &smet[wv][0];
#pragma unroll
    for (int j = 0; j < CH_; ++j) step(mp[j], yw + j * YPAD_);

    // transposed reduction: lane t' sums row t' (bank = (t'+h)%32, 2-way free)
    float r0 = 0.0f, r1 = 0.0f, r2 = 0.0f, r3 = 0.0f;
#pragma unroll
    for (int h = 0; h < CH_; h += 4) {
      r0 += yr[h + 0];
      r1 += yr[h + 1];
      r2 += yr[h + 2];
      r3 += yr[h + 3];
    }
    const int t_out = c * CH_ + lane;
    if (t_out < NT_) out[t_out * NS_ + site] = ((r0 + r1) + (r2 + r3)) + qb;

    if (c + 1 < NCHUNK_) smet[wv][lane] = compute_met(xnext);
  }
}

extern "C" void kernel_launch(void* const* d_in, const int* in_sizes, int n_in,
                              void* d_out, int out_size, void* d_ws, size_t ws_size,
                              hipStream_t stream) {
  const float* x    = (const float*)d_in[0];
  const float* xc   = (const float*)d_in[1];
  const float* fc_w = (const float*)d_in[2];
  const float* fc_b = (const float*)d_in[3];
  float* out = (float*)d_out;

  // 1024 sites, one wave each; 8 waves/block -> 128 blocks on 128 CUs,
  // 2 waves/SIMD so the HW scheduler hides recurrence + LDS stalls.
  hipLaunchKernelGGL(waternet_scan, dim3(NS_ / WPB_), dim3(WPB_ * 64), 0, stream,
                     x, xc, fc_w, fc_b, out);
}